// Round 2
// baseline (1328.014 us; speedup 1.0000x reference)
//
#include <hip/hip_runtime.h>
#include <hip/hip_bf16.h>
#include <stdint.h>

#define BATCH 64
#define SEQ   2048
#define VDIM  1024
#define HDIM  1024

typedef __bf16 b8v __attribute__((ext_vector_type(8)));
typedef __bf16 b4v __attribute__((ext_vector_type(4)));
typedef float f32x4 __attribute__((ext_vector_type(4)));
typedef unsigned short u16x8 __attribute__((ext_vector_type(8)));

__device__ __forceinline__ float bf2f(unsigned short u) {
    union { unsigned int i; float f; } cv; cv.i = ((unsigned int)u) << 16; return cv.f;
}

// pack 2 fp32 -> 2 bf16 (RNE). Order-sensitive callers must NOT use this
// (hardware pk order unverified); safe for GEMM LDS staging only, where a
// consistent pairwise permutation of k cancels between A and B fragments.
__device__ __forceinline__ unsigned int pack_bf16_2(float a, float b) {
#if __has_builtin(__builtin_amdgcn_cvt_pk_bf16_f32)
    auto t = __builtin_amdgcn_cvt_pk_bf16_f32(a, b);
    unsigned int r; __builtin_memcpy(&r, &t, 4); return r;
#else
    union { float f; unsigned int u; } ca, cb; ca.f = a; cb.f = b;
    unsigned int ra = ca.u + 0x7FFF + ((ca.u >> 16) & 1);
    unsigned int rb = cb.u + 0x7FFF + ((cb.u >> 16) & 1);
    return (ra >> 16) | (rb & 0xFFFF0000u);
#endif
}

__device__ __forceinline__ void gload_lds16(const unsigned short* g, unsigned short* l) {
    __builtin_amdgcn_global_load_lds(
        (const __attribute__((address_space(1))) unsigned int*)g,
        (__attribute__((address_space(3))) unsigned int*)l, 16, 0, 0);
}

// -------- fp32 -> bf16 elementwise (position-exact: plain casts) --------
__global__ __launch_bounds__(256) void cvt_bf16_kernel(
    const float* __restrict__ in, unsigned short* __restrict__ out, long n4)
{
    long g = (long)blockIdx.x * 256 + threadIdx.x;   // one float4 per thread
    if (g >= n4) return;
    float4 a = *(const float4*)(in + g * 4);
    b4v o = {(__bf16)a.x, (__bf16)a.y, (__bf16)a.z, (__bf16)a.w};
    *(b4v*)(out + g * 4) = o;
}

// -------- hq[b][h] = q[b]·W_q[h] + b_q[h] + b_v[h] (all fp32, exact) --------
__global__ __launch_bounds__(256) void hq_kernel(
    const float* __restrict__ q, const float* __restrict__ Wq,
    const float* __restrict__ bq, const float* __restrict__ bv,
    float* __restrict__ hq)
{
    int g = blockIdx.x * 256 + threadIdx.x;   // 65536 threads
    int b = g >> 10, h = g & 1023;
    const float4* qr = (const float4*)(q + ((size_t)b << 10));
    const float4* wr = (const float4*)(Wq + ((size_t)h << 10));
    float acc = 0.f;
    #pragma unroll 8
    for (int k = 0; k < 256; ++k) {
        float4 qa = qr[k], wa = wr[k];
        acc += qa.x*wa.x + qa.y*wa.y + qa.z*wa.z + qa.w*wa.w;
    }
    hq[g] = acc + bq[h] + bv[h];
}

// ======== shared epilogue (logit accumulation) as a macro body ========
// C[m][n]: m = wave_m + i*16 + quad*4 + r, n = wave_n + j*16 + col; b = m & 63
#define GEMM_EPILOGUE()                                                        \
    float rowsum[4][4];                                                        \
    _Pragma("unroll") for (int i = 0; i < 4; ++i)                              \
        _Pragma("unroll") for (int r = 0; r < 4; ++r) rowsum[i][r] = 0.f;      \
    _Pragma("unroll") for (int j = 0; j < 4; ++j) {                            \
        const int h = n_tile*128 + wave_n + j*16 + col;                        \
        const float wo = Wo[h];                                                \
        _Pragma("unroll") for (int i = 0; i < 4; ++i) {                        \
            const int brow = i*16 + quad*4;                                    \
            _Pragma("unroll") for (int r = 0; r < 4; ++r) {                    \
                float x = acc[i][j][r] + hq[(brow + r)*HDIM + h];              \
                float t = __expf(2.f * x);                                     \
                rowsum[i][r] += wo * (1.f - 2.f / (t + 1.f));                  \
            }                                                                  \
        }                                                                      \
    }                                                                          \
    _Pragma("unroll") for (int off = 1; off < 16; off <<= 1)                   \
        _Pragma("unroll") for (int i = 0; i < 4; ++i)                          \
            _Pragma("unroll") for (int r = 0; r < 4; ++r)                      \
                rowsum[i][r] += __shfl_xor(rowsum[i][r], off, 64);             \
    if (col == 0) {                                                            \
        _Pragma("unroll") for (int i = 0; i < 4; ++i)                          \
            _Pragma("unroll") for (int r = 0; r < 4; ++r)                      \
                atomicAdd(&logit_lds[wave_m + i*16 + quad*4 + r], rowsum[i][r]); \
    }                                                                          \
    __syncthreads();                                                           \
    if (tid < 128) {                                                           \
        const int b = tid & 63;                                                \
        const int s = m_tile*2 + (tid >> 6);                                   \
        atomicAdd(&logit[b*SEQ + s], logit_lds[tid]);                          \
    }

// -------- Path A: bf16 inputs (pre-converted), global_load_lds staging --------
__global__ __launch_bounds__(256) void fused_bf16(
    const unsigned short* __restrict__ v, const unsigned short* __restrict__ Wv,
    const float* __restrict__ Wo, const float* __restrict__ hq,
    float* __restrict__ logit)
{
    __shared__ __align__(16) unsigned short ldsA[128*32];
    __shared__ __align__(16) unsigned short ldsB[128*32];
    __shared__ float logit_lds[128];

    const int tid  = threadIdx.x;
    const int w    = tid >> 6;
    const int lane = tid & 63;
    const int col  = lane & 15;
    const int quad = lane >> 4;
    const int wave_m = (w >> 1) << 6;
    const int wave_n = (w & 1) << 6;
    const int n_tile = blockIdx.x;
    const int m_tile = blockIdx.y;

    if (tid < 128) logit_lds[tid] = 0.f;

    f32x4 acc[4][4];
    #pragma unroll
    for (int i = 0; i < 4; ++i)
        #pragma unroll
        for (int j = 0; j < 4; ++j) acc[i][j] = (f32x4)(0.f);

    const int srow = (w << 5) + (lane >> 2);
    const int scol = (lane & 3) << 3;
    const unsigned short* gA = v  + (size_t)(m_tile * 128 + srow) * VDIM + scol;
    const unsigned short* gB = Wv + (size_t)(n_tile * 128 + srow) * VDIM + scol;
    unsigned short* lA = ldsA + (w << 10) + (lane << 3);
    unsigned short* lB = ldsB + (w << 10) + (lane << 3);

    for (int kt = 0; kt < 32; ++kt) {
        const int ko = kt << 5;
        __syncthreads();
        gload_lds16(gA + ko,           lA);
        gload_lds16(gA + ko + 16*VDIM, lA + 512);
        gload_lds16(gB + ko,           lB);
        gload_lds16(gB + ko + 16*VDIM, lB + 512);
        __syncthreads();

        b8v aF[4], bF[4];
        #pragma unroll
        for (int i = 0; i < 4; ++i)
            aF[i] = *(const b8v*)(ldsA + ((wave_m + i*16 + col) << 5) + (quad << 3));
        #pragma unroll
        for (int j = 0; j < 4; ++j)
            bF[j] = *(const b8v*)(ldsB + ((wave_n + j*16 + col) << 5) + (quad << 3));
        #pragma unroll
        for (int i = 0; i < 4; ++i)
            #pragma unroll
            for (int j = 0; j < 4; ++j)
                acc[i][j] = __builtin_amdgcn_mfma_f32_16x16x32_bf16(aF[i], bF[j], acc[i][j], 0, 0, 0);
    }

    GEMM_EPILOGUE()
}

// -------- Path B: fp32 inputs, VGPR staging + cvt at LDS-write --------
__global__ __launch_bounds__(256) void fused_f32(
    const float* __restrict__ v, const float* __restrict__ Wv,
    const float* __restrict__ Wo, const float* __restrict__ hq,
    float* __restrict__ logit)
{
    __shared__ __align__(16) unsigned short ldsA[128*32];
    __shared__ __align__(16) unsigned short ldsB[128*32];
    __shared__ float logit_lds[128];

    const int tid  = threadIdx.x;
    const int w    = tid >> 6;
    const int lane = tid & 63;
    const int col  = lane & 15;
    const int quad = lane >> 4;
    const int wave_m = (w >> 1) << 6;
    const int wave_n = (w & 1) << 6;
    const int n_tile = blockIdx.x;
    const int m_tile = blockIdx.y;

    if (tid < 128) logit_lds[tid] = 0.f;

    f32x4 acc[4][4];
    #pragma unroll
    for (int i = 0; i < 4; ++i)
        #pragma unroll
        for (int j = 0; j < 4; ++j) acc[i][j] = (f32x4)(0.f);

    // staging: lane covers row (w*32 + r*8 + (lane>>3)), floats (lane&7)*4..+3
    const int srow8 = lane >> 3;
    const int scolf = (lane & 7) << 2;
    const float* gA = v  + (size_t)(m_tile * 128 + w*32 + srow8) * VDIM + scolf;
    const float* gB = Wv + (size_t)(n_tile * 128 + w*32 + srow8) * VDIM + scolf;
    unsigned short* lA = ldsA + (w*32 + srow8)*32 + ((lane & 7) << 2);
    unsigned short* lB = ldsB + (w*32 + srow8)*32 + ((lane & 7) << 2);

    float4 ra[4], rb[4];
    #pragma unroll
    for (int r = 0; r < 4; ++r) {
        ra[r] = *(const float4*)(gA + r*8*VDIM);
        rb[r] = *(const float4*)(gB + r*8*VDIM);
    }

    for (int kt = 0; kt < 32; ++kt) {
        __syncthreads();      // frag reads of kt-1 complete
        #pragma unroll
        for (int r = 0; r < 4; ++r) {
            uint2 pa = { pack_bf16_2(ra[r].x, ra[r].y), pack_bf16_2(ra[r].z, ra[r].w) };
            uint2 pb = { pack_bf16_2(rb[r].x, rb[r].y), pack_bf16_2(rb[r].z, rb[r].w) };
            *(uint2*)(lA + r*256) = pa;
            *(uint2*)(lB + r*256) = pb;
        }
        __syncthreads();      // staging visible

        // prefetch next K-tile; flies during the MFMAs below
        if (kt < 31) {
            const int ko = (kt + 1) << 5;
            #pragma unroll
            for (int r = 0; r < 4; ++r) {
                ra[r] = *(const float4*)(gA + ko + r*8*VDIM);
                rb[r] = *(const float4*)(gB + ko + r*8*VDIM);
            }
        }

        b8v aF[4], bF[4];
        #pragma unroll
        for (int i = 0; i < 4; ++i)
            aF[i] = *(const b8v*)(ldsA + ((wave_m + i*16 + col) << 5) + (quad << 3));
        #pragma unroll
        for (int j = 0; j < 4; ++j)
            bF[j] = *(const b8v*)(ldsB + ((wave_n + j*16 + col) << 5) + (quad << 3));
        #pragma unroll
        for (int i = 0; i < 4; ++i)
            #pragma unroll
            for (int j = 0; j < 4; ++j)
                acc[i][j] = __builtin_amdgcn_mfma_f32_16x16x32_bf16(aF[i], bF[j], acc[i][j], 0, 0, 0);
    }

    GEMM_EPILOGUE()
}

// -------- softmax over S per b; writes p (fp32) to d_out and normalized p in-place --------
__global__ __launch_bounds__(256) void softmax_kernel(float* __restrict__ logit,
                                                      float* __restrict__ pout)
{
    const int b = blockIdx.x, tid = threadIdx.x;
    float* row = logit + b * SEQ;
    __shared__ float red[4];

    float e[8];
    float lmax = -1e30f;
    #pragma unroll
    for (int k = 0; k < 8; ++k) { e[k] = row[tid + k*256]; lmax = fmaxf(lmax, e[k]); }
    #pragma unroll
    for (int off = 32; off > 0; off >>= 1) lmax = fmaxf(lmax, __shfl_xor(lmax, off, 64));
    if ((tid & 63) == 0) red[tid >> 6] = lmax;
    __syncthreads();
    lmax = fmaxf(fmaxf(red[0], red[1]), fmaxf(red[2], red[3]));
    __syncthreads();
    float lsum = 0.f;
    #pragma unroll
    for (int k = 0; k < 8; ++k) { e[k] = __expf(e[k] - lmax); lsum += e[k]; }
    #pragma unroll
    for (int off = 32; off > 0; off >>= 1) lsum += __shfl_xor(lsum, off, 64);
    if ((tid & 63) == 0) red[tid >> 6] = lsum;
    __syncthreads();
    lsum = red[0] + red[1] + red[2] + red[3];
    const float inv = 1.f / lsum;
    #pragma unroll
    for (int k = 0; k < 8; ++k) {
        const int s = tid + k*256;
        const float pv = e[k] * inv;
        row[s] = pv;
        pout[b*SEQ + s] = pv;
    }
}

// -------- ctx[b][:] = sum_s p[b][s] * v[s][b][:] --------
__global__ __launch_bounds__(128) void ctx_f32(
    const float* __restrict__ v, const float* __restrict__ p, float* __restrict__ ctx)
{
    const int b = blockIdx.y, sc = blockIdx.x, tid = threadIdx.x;
    float acc[8];
    #pragma unroll
    for (int e = 0; e < 8; ++e) acc[e] = 0.f;
    for (int s = sc*128; s < sc*128 + 128; ++s) {
        const float pv = p[b*SEQ + s];
        const float4* vp = (const float4*)(v + (size_t)(s*64 + b) * VDIM + tid*8);
        float4 v0 = vp[0], v1 = vp[1];
        acc[0] = fmaf(pv, v0.x, acc[0]); acc[1] = fmaf(pv, v0.y, acc[1]);
        acc[2] = fmaf(pv, v0.z, acc[2]); acc[3] = fmaf(pv, v0.w, acc[3]);
        acc[4] = fmaf(pv, v1.x, acc[4]); acc[5] = fmaf(pv, v1.y, acc[5]);
        acc[6] = fmaf(pv, v1.z, acc[6]); acc[7] = fmaf(pv, v1.w, acc[7]);
    }
    #pragma unroll
    for (int e = 0; e < 8; ++e) atomicAdd(&ctx[b*VDIM + tid*8 + e], acc[e]);
}

__global__ __launch_bounds__(128) void ctx_bf16(
    const unsigned short* __restrict__ v, const float* __restrict__ p, float* __restrict__ ctx)
{
    const int b = blockIdx.y, sc = blockIdx.x, tid = threadIdx.x;
    float acc[8];
    #pragma unroll
    for (int e = 0; e < 8; ++e) acc[e] = 0.f;
    for (int s = sc*128; s < sc*128 + 128; ++s) {
        const float pv = p[b*SEQ + s];
        u16x8 val = *(const u16x8*)(v + (size_t)(s*64 + b) * VDIM + tid*8);
        #pragma unroll
        for (int e = 0; e < 8; ++e) acc[e] = fmaf(pv, bf2f(val[e]), acc[e]);
    }
    #pragma unroll
    for (int e = 0; e < 8; ++e) atomicAdd(&ctx[b*VDIM + tid*8 + e], acc[e]);
}

__global__ __launch_bounds__(256) void copy_kernel(const float* __restrict__ src,
                                                   float* __restrict__ dst)
{
    int g = blockIdx.x * 256 + threadIdx.x;
    dst[g] = src[g];
}

extern "C" void kernel_launch(void* const* d_in, const int* in_sizes, int n_in,
                              void* d_out, int out_size, void* d_ws, size_t ws_size,
                              hipStream_t stream)
{
    const float* q  = (const float*)d_in[0];
    const float* v  = (const float*)d_in[1];
    const float* Wv = (const float*)d_in[2];
    const float* bv = (const float*)d_in[3];
    const float* Wq = (const float*)d_in[4];
    const float* bq = (const float*)d_in[5];
    const float* Wo = (const float*)d_in[6];
    // d_in[7] = b_o: cancels under softmax shift-invariance

    float* hq_ws    = (float*)d_ws;                  // 65536 fp32
    float* logit_ws = hq_ws + 65536;                 // 131072 fp32
    float* ctx_ws   = logit_ws + 131072;             // 65536 fp32
    unsigned short* vb  = (unsigned short*)(ctx_ws + 65536);   // 134217728 bf16 (path A)
    unsigned short* Wvb = vb + (size_t)SEQ*BATCH*VDIM;         // 1048576 bf16 (path A)

    const size_t needA = (size_t)(65536 + 131072 + 65536) * 4
                       + ((size_t)SEQ*BATCH*VDIM + (size_t)HDIM*VDIM) * 2;
    const bool bigws = ws_size >= needA;

    float* out_ctx = (float*)d_out;          // [1,64,1024]
    float* out_p   = out_ctx + 65536;        // [64,2048]

    hipMemsetAsync(logit_ws, 0, (131072 + 65536) * sizeof(float), stream);
    hq_kernel<<<256, 256, 0, stream>>>(q, Wq, bq, bv, hq_ws);

    if (bigws) {
        cvt_bf16_kernel<<<(SEQ*BATCH*VDIM/4 + 255)/256, 256, 0, stream>>>(v,  vb,  (long)SEQ*BATCH*VDIM/4);
        cvt_bf16_kernel<<<(HDIM*VDIM/4 + 255)/256,      256, 0, stream>>>(Wv, Wvb, (long)HDIM*VDIM/4);
        fused_bf16<<<dim3(8, 1024), 256, 0, stream>>>(vb, Wvb, Wo, hq_ws, logit_ws);
        softmax_kernel<<<64, 256, 0, stream>>>(logit_ws, out_p);
        ctx_bf16<<<dim3(16, 64), 128, 0, stream>>>(vb, logit_ws, ctx_ws);
    } else {
        fused_f32<<<dim3(8, 1024), 256, 0, stream>>>(v, Wv, Wo, hq_ws, logit_ws);
        softmax_kernel<<<64, 256, 0, stream>>>(logit_ws, out_p);
        ctx_f32<<<dim3(16, 64), 128, 0, stream>>>(v, logit_ws, ctx_ws);
    }
    copy_kernel<<<256, 256, 0, stream>>>(ctx_ws, out_ctx);
}